// Round 6
// baseline (162.847 us; speedup 1.0000x reference)
//
#include <hip/hip_runtime.h>
#include <math.h>

#define BB 16
#define SS 8192
#define DD 512
#define HH 512
#define NEG_INF (-1e18f)
#define BPB 64   // score-blocks per batch: 16*64 = 1024 blocks = 4 per CU

__device__ __forceinline__ float dot8(float4 a0, float4 a1, float4 b0, float4 b1) {
  return a0.x*b0.x + a0.y*b0.y + a0.z*b0.z + a0.w*b0.w
       + a1.x*b1.x + a1.y*b1.y + a1.z*b1.z + a1.w*b1.w;
}

// DPP wave64 sum: result valid in lane 63 only. VALU-only (no DS pipe).
template <int CTRL>
__device__ __forceinline__ float dpp_add0(float x) {
  return x + __int_as_float(__builtin_amdgcn_update_dpp(
      0, __float_as_int(x), CTRL, 0xf, 0xf, true));
}
__device__ __forceinline__ float wave_red_sum(float x) {
  x = dpp_add0<0x111>(x);  // row_shr:1
  x = dpp_add0<0x112>(x);  // row_shr:2
  x = dpp_add0<0x114>(x);  // row_shr:4
  x = dpp_add0<0x118>(x);  // row_shr:8
  x = dpp_add0<0x142>(x);  // row_bcast:15
  x = dpp_add0<0x143>(x);  // row_bcast:31
  return x;                // lane 63 = full sum
}
__device__ __forceinline__ float lane63(float x) {
  return __int_as_float(__builtin_amdgcn_readlane(__float_as_int(x), 63));
}
template <int CTRL>
__device__ __forceinline__ float dpp_maxstep(float x) {
  int y = __builtin_amdgcn_update_dpp(
      __float_as_int(x), __float_as_int(x), CTRL, 0xf, 0xf, false);
  return fmaxf(x, __int_as_float(y));
}
__device__ __forceinline__ float wave_red_max(float x) {
  x = dpp_maxstep<0x111>(x); x = dpp_maxstep<0x112>(x);
  x = dpp_maxstep<0x114>(x); x = dpp_maxstep<0x118>(x);
  x = dpp_maxstep<0x142>(x); x = dpp_maxstep<0x143>(x);
  return x;                // lane 63 = full max
}

// K0: 129 blocks x 256 threads.
// blocks [0,64):   v[j*8 .. j*8+8)  = sum_h wout[h]*Wk[h][slice]
// blocks [64,128): w2[j*8 .. j*8+8) = sum_h wout[h]*Wq[h][slice]
// block 128:       c0 = sum_h wout[h]*(bq[h]+bk[h]); zero the per-b counters
__global__ __launch_bounds__(256) void k_prep(
    const float* __restrict__ Wq, const float* __restrict__ Wk,
    const float* __restrict__ wout, const float* __restrict__ bq,
    const float* __restrict__ bk, float* __restrict__ v,
    float* __restrict__ w2, float* __restrict__ c0,
    unsigned* __restrict__ cnt)
{
  int blk = blockIdx.x;
  int t = threadIdx.x;
  if (blk == 128) {
    if (t < BB) cnt[t] = 0u;
    if (t < 64) {
      float part = 0.f;
      #pragma unroll
      for (int i = 0; i < 8; ++i) {
        int h = t + 64 * i;
        part += wout[h] * (bq[h] + bk[h]);
      }
      part = wave_red_sum(part);
      if (t == 63) c0[0] = part;
    }
    return;
  }
  int j = blk & 63;
  const float* W = (blk < 64) ? Wk : Wq;
  float* outp = (blk < 64) ? v : w2;
  int dsl = j * 8;
  int h0 = t, h1 = t + 256;
  const float4* r0 = (const float4*)(W + (size_t)h0 * DD + dsl);
  const float4* r1 = (const float4*)(W + (size_t)h1 * DD + dsl);
  float4 a0 = r0[0], a1 = r0[1], b0 = r1[0], b1 = r1[1];
  float wA = wout[h0], wB = wout[h1];
  float acc[8];
  acc[0] = wA*a0.x + wB*b0.x; acc[1] = wA*a0.y + wB*b0.y;
  acc[2] = wA*a0.z + wB*b0.z; acc[3] = wA*a0.w + wB*b0.w;
  acc[4] = wA*a1.x + wB*b1.x; acc[5] = wA*a1.y + wB*b1.y;
  acc[6] = wA*a1.z + wB*b1.z; acc[7] = wA*a1.w + wB*b1.w;
  __shared__ float red[256][9];
  #pragma unroll
  for (int k = 0; k < 8; ++k) red[t][k] = acc[k];
  __syncthreads();
  for (int st = 128; st; st >>= 1) {
    if (t < st) {
      #pragma unroll
      for (int k = 0; k < 8; ++k) red[t][k] += red[t + st][k];
    }
    __syncthreads();
  }
  if (t < 8) outp[dsl + t] = red[0][t];
}

// K1: streaming pass + fused last-block epilogue.
// grid = B*BPB blocks x 256 threads (4 waves). 4 rows/wave/iter, depth-1
// prefetch, DPP reductions, inline qc. After publishing its partial, the
// last-arriving block per b (device-scope atomic counter) combines all 64
// partials and computes attn[b][:] = Wk.ubar + bk inline.
__global__ __launch_bounds__(256, 4) void k_score(
    const float* __restrict__ key, const int* __restrict__ mask,
    const float* __restrict__ query, const float* __restrict__ ws_v,
    const float* __restrict__ ws_w2, const float* __restrict__ ws_c0,
    const float* __restrict__ Wk, const float* __restrict__ bk,
    float* __restrict__ scores, float* __restrict__ partials,
    unsigned* __restrict__ cnt, float* __restrict__ attn)
{
  int blk = blockIdx.x;
  int b = blk / BPB;
  int pb = blk % BPB;
  const int rows = SS / BPB;       // 128
  int s0 = pb * rows;
  int wave = threadIdx.x >> 6;
  int lane = threadIdx.x & 63;

  __shared__ __align__(16) float smem[4 * DD];  // ls_u phase 1; ubar+fsh phase 2
  __shared__ float ls_m[4], ls_l[4], dsh;
  __shared__ unsigned sh_old;

  const float4* vv = (const float4*)ws_v;
  float4 v0 = vv[lane], v1 = vv[64 + lane];

  // qc = query[b].w2 + c0, computed redundantly per wave (L2-hot inputs)
  float qc;
  {
    const float4* q4 = (const float4*)(query + (size_t)b * DD);
    const float4* w24 = (const float4*)ws_w2;
    float qp = wave_red_sum(dot8(q4[lane], q4[64 + lane], w24[lane], w24[64 + lane]));
    qc = lane63(qp) + ws_c0[0];
  }

  const float4* keyb = (const float4*)(key + (size_t)b * SS * DD);
  const int* maskb = mask + b * SS;

  float m = -INFINITY, l = 0.f;
  float4 u0 = {0.f,0.f,0.f,0.f}, u1 = {0.f,0.f,0.f,0.f};

  const int nit = rows / 16;  // 8 iterations, 16 rows/block/iter
  int s = s0 + wave * 4;

  float4 r0a, r0b, r1a, r1b, r2a, r2b, r3a, r3b;
  {
    const float4* p0 = keyb + (size_t)s * (DD / 4);
    r0a = p0[lane];       r0b = p0[64 + lane];
    r1a = p0[128 + lane]; r1b = p0[192 + lane];
    r2a = p0[256 + lane]; r2b = p0[320 + lane];
    r3a = p0[384 + lane]; r3b = p0[448 + lane];
  }
  int4 mk = *(const int4*)(maskb + s);

  for (int i = 0; i < nit; ++i) {
    float4 n0a=r0a, n0b=r0b, n1a=r1a, n1b=r1b, n2a=r2a, n2b=r2b, n3a=r3a, n3b=r3b;
    int4 nmk = {0,0,0,0};
    if (i + 1 < nit) {
      const float4* p0 = keyb + (size_t)(s + 16) * (DD / 4);
      n0a = p0[lane];       n0b = p0[64 + lane];
      n1a = p0[128 + lane]; n1b = p0[192 + lane];
      n2a = p0[256 + lane]; n2b = p0[320 + lane];
      n3a = p0[384 + lane]; n3b = p0[448 + lane];
      nmk = *(const int4*)(maskb + s + 16);
    }
    float p0v = wave_red_sum(dot8(r0a, r0b, v0, v1));
    float p1v = wave_red_sum(dot8(r1a, r1b, v0, v1));
    float p2v = wave_red_sum(dot8(r2a, r2b, v0, v1));
    float p3v = wave_red_sum(dot8(r3a, r3b, v0, v1));
    float d0 = lane63(p0v), d1 = lane63(p1v);
    float d2 = lane63(p2v), d3 = lane63(p3v);
    float sc0 = mk.x ? NEG_INF : (d0 + qc);
    float sc1 = mk.y ? NEG_INF : (d1 + qc);
    float sc2 = mk.z ? NEG_INF : (d2 + qc);
    float sc3 = mk.w ? NEG_INF : (d3 + qc);
    if (lane == 0) {
      float4 st = {sc0, sc1, sc2, sc3};
      *(float4*)(scores + (size_t)b * SS + s) = st;
    }
    float mn = fmaxf(fmaxf(fmaxf(sc0, sc1), fmaxf(sc2, sc3)), m);
    if (mn > m) {  // wave-uniform
      float sc = __expf(m - mn);  // exp(-inf)=0 on first update
      l *= sc;
      u0.x *= sc; u0.y *= sc; u0.z *= sc; u0.w *= sc;
      u1.x *= sc; u1.y *= sc; u1.z *= sc; u1.w *= sc;
      m = mn;
    }
    float e0 = __expf(sc0 - m), e1 = __expf(sc1 - m);
    float e2 = __expf(sc2 - m), e3 = __expf(sc3 - m);
    l += (e0 + e1) + (e2 + e3);
    u0.x += e0*r0a.x + e1*r1a.x + e2*r2a.x + e3*r3a.x;
    u0.y += e0*r0a.y + e1*r1a.y + e2*r2a.y + e3*r3a.y;
    u0.z += e0*r0a.z + e1*r1a.z + e2*r2a.z + e3*r3a.z;
    u0.w += e0*r0a.w + e1*r1a.w + e2*r2a.w + e3*r3a.w;
    u1.x += e0*r0b.x + e1*r1b.x + e2*r2b.x + e3*r3b.x;
    u1.y += e0*r0b.y + e1*r1b.y + e2*r2b.y + e3*r3b.y;
    u1.z += e0*r0b.z + e1*r1b.z + e2*r2b.z + e3*r3b.z;
    u1.w += e0*r0b.w + e1*r1b.w + e2*r2b.w + e3*r3b.w;
    r0a=n0a; r0b=n0b; r1a=n1a; r1b=n1b; r2a=n2a; r2b=n2b; r3a=n3a; r3b=n3b;
    mk = nmk; s += 16;
  }

  // block combine across 4 waves (ls_u aliased onto smem)
  smem[wave * DD + 4 * lane + 0] = u0.x; smem[wave * DD + 4 * lane + 1] = u0.y;
  smem[wave * DD + 4 * lane + 2] = u0.z; smem[wave * DD + 4 * lane + 3] = u0.w;
  smem[wave * DD + 256 + 4 * lane + 0] = u1.x; smem[wave * DD + 256 + 4 * lane + 1] = u1.y;
  smem[wave * DD + 256 + 4 * lane + 2] = u1.z; smem[wave * DD + 256 + 4 * lane + 3] = u1.w;
  if (lane == 0) { ls_m[wave] = m; ls_l[wave] = l; }
  __syncthreads();

  float M = fmaxf(fmaxf(ls_m[0], ls_m[1]), fmaxf(ls_m[2], ls_m[3]));
  float f0 = __expf(ls_m[0] - M), f1 = __expf(ls_m[1] - M);
  float f2 = __expf(ls_m[2] - M), f3 = __expf(ls_m[3] - M);
  int d = threadIdx.x;  // 0..255
  float ua = smem[d] * f0 + smem[DD + d] * f1
           + smem[2 * DD + d] * f2 + smem[3 * DD + d] * f3;
  float ub = smem[d + 256] * f0 + smem[DD + d + 256] * f1
           + smem[2 * DD + d + 256] * f2 + smem[3 * DD + d + 256] * f3;
  float* part = partials + (size_t)(b * BPB + pb) * (DD + 2);
  part[2 + d] = ua;
  part[2 + 256 + d] = ub;
  if (threadIdx.x == 0) {
    part[0] = M;
    part[1] = ls_l[0] * f0 + ls_l[1] * f1 + ls_l[2] * f2 + ls_l[3] * f3;
  }

  // publish partial; last-arriving block per b runs the epilogue
  __syncthreads();                    // all partial stores drained (vmcnt 0)
  if (threadIdx.x == 0) {
    __threadfence();                  // device-scope release
    sh_old = atomicAdd(&cnt[b], 1u);  // device-scope by default
  }
  __syncthreads();
  if (sh_old != BPB - 1) return;

  // ---- epilogue (one block per b) ----
  __threadfence();                    // device-scope acquire
  float* ubar = smem;                 // [0, 512) — smem free after barrier
  float* fsh  = smem + DD;            // [512, 576)
  const float* pbase = partials + (size_t)b * BPB * (DD + 2);
  int tid = threadIdx.x;

  if (tid < 64) {
    float mp = pbase[tid * (DD + 2)];
    float lp = pbase[tid * (DD + 2) + 1];
    float Mx = lane63(wave_red_max(mp));
    float f = __expf(mp - Mx);
    fsh[tid] = f;
    float dn = wave_red_sum(lp * f);
    if (tid == 63) dsh = dn;
  }
  __syncthreads();

  float inv = 1.f / dsh;
  float sa = 0.f, sb = 0.f;
  #pragma unroll 8
  for (int p = 0; p < BPB; ++p) {
    float f = fsh[p];
    sa += pbase[p * (DD + 2) + 2 + tid] * f;
    sb += pbase[p * (DD + 2) + 2 + 256 + tid] * f;
  }
  ubar[tid] = sa * inv;
  ubar[tid + 256] = sb * inv;
  __syncthreads();

  const float4* ub4 = (const float4*)ubar;
  float4 x0 = ub4[lane], x1 = ub4[64 + lane];
  #pragma unroll 4
  for (int j = 0; j < 128; ++j) {
    int h = wave * 128 + j;
    const float4* wr = (const float4*)(Wk + (size_t)h * DD);
    float p = wave_red_sum(dot8(wr[lane], wr[64 + lane], x0, x1));
    if (lane == 63) attn[b * HH + h] = p + bk[h];
  }
}

extern "C" void kernel_launch(void* const* d_in, const int* in_sizes, int n_in,
                              void* d_out, int out_size, void* d_ws, size_t ws_size,
                              hipStream_t stream) {
  const float* query = (const float*)d_in[0];
  const float* key   = (const float*)d_in[1];
  const int*   mask  = (const int*)d_in[2];
  const float* Wq    = (const float*)d_in[3];
  const float* bq    = (const float*)d_in[4];
  const float* Wk    = (const float*)d_in[5];
  const float* bk    = (const float*)d_in[6];
  const float* wout  = (const float*)d_in[7];

  float* out    = (float*)d_out;
  float* attn   = out;                 // (B, H)
  float* scores = out + BB * HH;       // (B, S)
  float* ws     = (float*)d_ws;

  // ws layout (floats)
  float* ws_v  = ws;                     // 512
  float* ws_w2 = ws + 512;               // 512
  float* ws_c0 = ws + 1024;              // 1
  unsigned* cnt = (unsigned*)(ws + 1040); // 16
  float* partials = ws + 1056;           // B*BPB*(D+2) ~ 2.1 MB

  k_prep<<<dim3(129), dim3(256), 0, stream>>>(Wq, Wk, wout, bq, bk,
                                              ws_v, ws_w2, ws_c0, cnt);
  k_score<<<dim3(BB * BPB), dim3(256), 0, stream>>>(key, mask, query, ws_v,
                                                    ws_w2, ws_c0, Wk, bk,
                                                    scores, partials, cnt, attn);
}

// Round 7
// 60.855 us; speedup vs baseline: 2.6760x; 2.6760x over previous
//
#include <hip/hip_runtime.h>
#include <math.h>

#define BB 16
#define SS 8192
#define DD 512
#define HH 512
#define NEG_INF (-1e18f)
#define BPB 64   // score-blocks per batch: 16*64 = 1024 blocks = 4 per CU

__device__ __forceinline__ float dot8(float4 a0, float4 a1, float4 b0, float4 b1) {
  return a0.x*b0.x + a0.y*b0.y + a0.z*b0.z + a0.w*b0.w
       + a1.x*b1.x + a1.y*b1.y + a1.z*b1.z + a1.w*b1.w;
}

// DPP wave64 sum: result valid in lane 63 only. VALU-only (no DS pipe).
template <int CTRL>
__device__ __forceinline__ float dpp_add0(float x) {
  return x + __int_as_float(__builtin_amdgcn_update_dpp(
      0, __float_as_int(x), CTRL, 0xf, 0xf, true));
}
__device__ __forceinline__ float wave_red_sum(float x) {
  x = dpp_add0<0x111>(x);  // row_shr:1
  x = dpp_add0<0x112>(x);  // row_shr:2
  x = dpp_add0<0x114>(x);  // row_shr:4
  x = dpp_add0<0x118>(x);  // row_shr:8
  x = dpp_add0<0x142>(x);  // row_bcast:15
  x = dpp_add0<0x143>(x);  // row_bcast:31
  return x;                // lane 63 = full sum
}
__device__ __forceinline__ float lane63(float x) {
  return __int_as_float(__builtin_amdgcn_readlane(__float_as_int(x), 63));
}
template <int CTRL>
__device__ __forceinline__ float dpp_maxstep(float x) {
  int y = __builtin_amdgcn_update_dpp(
      __float_as_int(x), __float_as_int(x), CTRL, 0xf, 0xf, false);
  return fmaxf(x, __int_as_float(y));
}
__device__ __forceinline__ float wave_red_max(float x) {
  x = dpp_maxstep<0x111>(x); x = dpp_maxstep<0x112>(x);
  x = dpp_maxstep<0x114>(x); x = dpp_maxstep<0x118>(x);
  x = dpp_maxstep<0x142>(x); x = dpp_maxstep<0x143>(x);
  return x;                // lane 63 = full max
}

// K0: 129 blocks x 256 threads, one launch, no stage-2 dependency.
// blocks [0,64):   v[j*8 .. j*8+8)  = sum_h wout[h]*Wk[h][slice]
// blocks [64,128): w2[j*8 .. j*8+8) = sum_h wout[h]*Wq[h][slice]
// block 128:       c0 = sum_h wout[h]*(bq[h]+bk[h])
__global__ __launch_bounds__(256) void k_prep(
    const float* __restrict__ Wq, const float* __restrict__ Wk,
    const float* __restrict__ wout, const float* __restrict__ bq,
    const float* __restrict__ bk, float* __restrict__ v,
    float* __restrict__ w2, float* __restrict__ c0)
{
  int blk = blockIdx.x;
  int t = threadIdx.x;
  if (blk == 128) {
    if (t < 64) {
      float part = 0.f;
      #pragma unroll
      for (int i = 0; i < 8; ++i) {
        int h = t + 64 * i;
        part += wout[h] * (bq[h] + bk[h]);
      }
      part = wave_red_sum(part);
      if (t == 63) c0[0] = part;
    }
    return;
  }
  int j = blk & 63;
  const float* W = (blk < 64) ? Wk : Wq;
  float* outp = (blk < 64) ? v : w2;
  int dsl = j * 8;
  int h0 = t, h1 = t + 256;
  const float4* r0 = (const float4*)(W + (size_t)h0 * DD + dsl);
  const float4* r1 = (const float4*)(W + (size_t)h1 * DD + dsl);
  float4 a0 = r0[0], a1 = r0[1], b0 = r1[0], b1 = r1[1];
  float wA = wout[h0], wB = wout[h1];
  float acc[8];
  acc[0] = wA*a0.x + wB*b0.x; acc[1] = wA*a0.y + wB*b0.y;
  acc[2] = wA*a0.z + wB*b0.z; acc[3] = wA*a0.w + wB*b0.w;
  acc[4] = wA*a1.x + wB*b1.x; acc[5] = wA*a1.y + wB*b1.y;
  acc[6] = wA*a1.z + wB*b1.z; acc[7] = wA*a1.w + wB*b1.w;
  __shared__ float red[256][9];
  #pragma unroll
  for (int k = 0; k < 8; ++k) red[t][k] = acc[k];
  __syncthreads();
  for (int st = 128; st; st >>= 1) {
    if (t < st) {
      #pragma unroll
      for (int k = 0; k < 8; ++k) red[t][k] += red[t + st][k];
    }
    __syncthreads();
  }
  if (t < 8) outp[dsl + t] = red[0][t];
}

// K1: main streaming pass. grid = B*BPB blocks x 256 threads (4 waves).
// 4 rows/wave/iter, depth-1 prefetch, DPP reductions, inline qc.
__global__ __launch_bounds__(256, 4) void k_score(
    const float* __restrict__ key, const int* __restrict__ mask,
    const float* __restrict__ query, const float* __restrict__ ws_v,
    const float* __restrict__ ws_w2, const float* __restrict__ ws_c0,
    float* __restrict__ scores, float* __restrict__ partials)
{
  int blk = blockIdx.x;
  int b = blk / BPB;
  int pb = blk % BPB;
  const int rows = SS / BPB;       // 128
  int s0 = pb * rows;
  int wave = threadIdx.x >> 6;
  int lane = threadIdx.x & 63;

  const float4* vv = (const float4*)ws_v;
  float4 v0 = vv[lane], v1 = vv[64 + lane];

  // qc = query[b].w2 + c0, computed redundantly per wave (L2-hot inputs)
  float qc;
  {
    const float4* q4 = (const float4*)(query + (size_t)b * DD);
    const float4* w24 = (const float4*)ws_w2;
    float qp = wave_red_sum(dot8(q4[lane], q4[64 + lane], w24[lane], w24[64 + lane]));
    qc = lane63(qp) + ws_c0[0];
  }

  const float4* keyb = (const float4*)(key + (size_t)b * SS * DD);
  const int* maskb = mask + b * SS;

  float m = -INFINITY, l = 0.f;
  float4 u0 = {0.f,0.f,0.f,0.f}, u1 = {0.f,0.f,0.f,0.f};

  const int nit = rows / 16;  // 8 iterations, 16 rows/block/iter
  int s = s0 + wave * 4;

  float4 r0a, r0b, r1a, r1b, r2a, r2b, r3a, r3b;
  {
    const float4* p0 = keyb + (size_t)s * (DD / 4);
    r0a = p0[lane];       r0b = p0[64 + lane];
    r1a = p0[128 + lane]; r1b = p0[192 + lane];
    r2a = p0[256 + lane]; r2b = p0[320 + lane];
    r3a = p0[384 + lane]; r3b = p0[448 + lane];
  }
  int4 mk = *(const int4*)(maskb + s);

  for (int i = 0; i < nit; ++i) {
    float4 n0a=r0a, n0b=r0b, n1a=r1a, n1b=r1b, n2a=r2a, n2b=r2b, n3a=r3a, n3b=r3b;
    int4 nmk = {0,0,0,0};
    if (i + 1 < nit) {
      const float4* p0 = keyb + (size_t)(s + 16) * (DD / 4);
      n0a = p0[lane];       n0b = p0[64 + lane];
      n1a = p0[128 + lane]; n1b = p0[192 + lane];
      n2a = p0[256 + lane]; n2b = p0[320 + lane];
      n3a = p0[384 + lane]; n3b = p0[448 + lane];
      nmk = *(const int4*)(maskb + s + 16);
    }
    // 4 independent DPP reduce chains (VALU only)
    float p0v = wave_red_sum(dot8(r0a, r0b, v0, v1));
    float p1v = wave_red_sum(dot8(r1a, r1b, v0, v1));
    float p2v = wave_red_sum(dot8(r2a, r2b, v0, v1));
    float p3v = wave_red_sum(dot8(r3a, r3b, v0, v1));
    float d0 = lane63(p0v), d1 = lane63(p1v);
    float d2 = lane63(p2v), d3 = lane63(p3v);
    float sc0 = mk.x ? NEG_INF : (d0 + qc);
    float sc1 = mk.y ? NEG_INF : (d1 + qc);
    float sc2 = mk.z ? NEG_INF : (d2 + qc);
    float sc3 = mk.w ? NEG_INF : (d3 + qc);
    if (lane == 0) {
      float4 st = {sc0, sc1, sc2, sc3};
      *(float4*)(scores + (size_t)b * SS + s) = st;
    }
    float mn = fmaxf(fmaxf(fmaxf(sc0, sc1), fmaxf(sc2, sc3)), m);
    if (mn > m) {  // wave-uniform
      float sc = __expf(m - mn);  // exp(-inf)=0 on first update
      l *= sc;
      u0.x *= sc; u0.y *= sc; u0.z *= sc; u0.w *= sc;
      u1.x *= sc; u1.y *= sc; u1.z *= sc; u1.w *= sc;
      m = mn;
    }
    float e0 = __expf(sc0 - m), e1 = __expf(sc1 - m);
    float e2 = __expf(sc2 - m), e3 = __expf(sc3 - m);
    l += (e0 + e1) + (e2 + e3);
    u0.x += e0*r0a.x + e1*r1a.x + e2*r2a.x + e3*r3a.x;
    u0.y += e0*r0a.y + e1*r1a.y + e2*r2a.y + e3*r3a.y;
    u0.z += e0*r0a.z + e1*r1a.z + e2*r2a.z + e3*r3a.z;
    u0.w += e0*r0a.w + e1*r1a.w + e2*r2a.w + e3*r3a.w;
    u1.x += e0*r0b.x + e1*r1b.x + e2*r2b.x + e3*r3b.x;
    u1.y += e0*r0b.y + e1*r1b.y + e2*r2b.y + e3*r3b.y;
    u1.z += e0*r0b.z + e1*r1b.z + e2*r2b.z + e3*r3b.z;
    u1.w += e0*r0b.w + e1*r1b.w + e2*r2b.w + e3*r3b.w;
    r0a=n0a; r0b=n0b; r1a=n1a; r1b=n1b; r2a=n2a; r2b=n2b; r3a=n3a; r3b=n3b;
    mk = nmk; s += 16;
  }

  // block combine across 4 waves
  __shared__ float ls_m[4], ls_l[4];
  __shared__ __align__(16) float ls_u[4][DD];
  ls_u[wave][4 * lane + 0] = u0.x; ls_u[wave][4 * lane + 1] = u0.y;
  ls_u[wave][4 * lane + 2] = u0.z; ls_u[wave][4 * lane + 3] = u0.w;
  ls_u[wave][256 + 4 * lane + 0] = u1.x; ls_u[wave][256 + 4 * lane + 1] = u1.y;
  ls_u[wave][256 + 4 * lane + 2] = u1.z; ls_u[wave][256 + 4 * lane + 3] = u1.w;
  if (lane == 0) { ls_m[wave] = m; ls_l[wave] = l; }
  __syncthreads();

  float M = fmaxf(fmaxf(ls_m[0], ls_m[1]), fmaxf(ls_m[2], ls_m[3]));
  float f0 = __expf(ls_m[0] - M), f1 = __expf(ls_m[1] - M);
  float f2 = __expf(ls_m[2] - M), f3 = __expf(ls_m[3] - M);
  int d = threadIdx.x;  // 0..255
  float ua = ls_u[0][d] * f0 + ls_u[1][d] * f1 + ls_u[2][d] * f2 + ls_u[3][d] * f3;
  float ub = ls_u[0][d + 256] * f0 + ls_u[1][d + 256] * f1
           + ls_u[2][d + 256] * f2 + ls_u[3][d + 256] * f3;
  float* part = partials + (size_t)(b * BPB + pb) * (DD + 2);
  part[2 + d] = ua;
  part[2 + 256 + d] = ub;
  if (threadIdx.x == 0) {
    part[0] = M;
    part[1] = ls_l[0] * f0 + ls_l[1] * f1 + ls_l[2] * f2 + ls_l[3] * f3;
  }
}

// K2: fused combine + attn. 256 blocks (b, hc) x 256 threads.
// Each block redundantly combines partials for its b (L2-resident), then
// computes 32 h-dots: attn[b][h] = Wk[h].ubar + bk[h].
__global__ __launch_bounds__(256) void k_out(
    const float* __restrict__ Wk, const float* __restrict__ bk,
    const float* __restrict__ partials, float* __restrict__ attn)
{
  int b = blockIdx.x >> 4;
  int hc = blockIdx.x & 15;
  int tid = threadIdx.x;
  int wave = tid >> 6, lane = tid & 63;
  __shared__ __align__(16) float ubar[DD];
  __shared__ float fsh[BPB];
  __shared__ float dsh;
  const float* pbase = partials + (size_t)b * BPB * (DD + 2);

  if (tid < 64) {
    float mp = pbase[tid * (DD + 2)];
    float lp = pbase[tid * (DD + 2) + 1];
    float M = lane63(wave_red_max(mp));
    float f = __expf(mp - M);
    fsh[tid] = f;
    float dn = wave_red_sum(lp * f);
    if (tid == 63) dsh = dn;
  }
  __syncthreads();

  float inv = 1.f / dsh;
  float ua = 0.f, ub_ = 0.f;
  #pragma unroll 8
  for (int p = 0; p < BPB; ++p) {
    float f = fsh[p];
    ua  += pbase[p * (DD + 2) + 2 + tid] * f;
    ub_ += pbase[p * (DD + 2) + 2 + 256 + tid] * f;
  }
  ubar[tid] = ua * inv;
  ubar[tid + 256] = ub_ * inv;
  __syncthreads();

  const float4* ub4 = (const float4*)ubar;
  float4 x0 = ub4[lane], x1 = ub4[64 + lane];
  #pragma unroll
  for (int j = 0; j < 8; ++j) {
    int h = hc * 32 + wave * 8 + j;
    const float4* wr = (const float4*)(Wk + (size_t)h * DD);
    float p = wave_red_sum(dot8(wr[lane], wr[64 + lane], x0, x1));
    if (lane == 63) attn[b * HH + h] = p + bk[h];
  }
}

extern "C" void kernel_launch(void* const* d_in, const int* in_sizes, int n_in,
                              void* d_out, int out_size, void* d_ws, size_t ws_size,
                              hipStream_t stream) {
  const float* query = (const float*)d_in[0];
  const float* key   = (const float*)d_in[1];
  const int*   mask  = (const int*)d_in[2];
  const float* Wq    = (const float*)d_in[3];
  const float* bq    = (const float*)d_in[4];
  const float* Wk    = (const float*)d_in[5];
  const float* bk    = (const float*)d_in[6];
  const float* wout  = (const float*)d_in[7];

  float* out    = (float*)d_out;
  float* attn   = out;                 // (B, H)
  float* scores = out + BB * HH;       // (B, S)
  float* ws     = (float*)d_ws;

  // ws layout (floats)
  float* ws_v  = ws;            // 512
  float* ws_w2 = ws + 512;      // 512
  float* ws_c0 = ws + 1024;     // 1 (pad to 1040)
  float* partials = ws + 1040;  // B*BPB*(D+2) ~ 2.06 MB

  k_prep<<<dim3(129), dim3(256), 0, stream>>>(Wq, Wk, wout, bq, bk,
                                              ws_v, ws_w2, ws_c0);
  k_score<<<dim3(BB * BPB), dim3(256), 0, stream>>>(key, mask, query, ws_v,
                                                    ws_w2, ws_c0, scores, partials);
  k_out<<<dim3(BB * 16), dim3(256), 0, stream>>>(Wk, bk, partials, attn);
}